// Round 2
// baseline (548.398 us; speedup 1.0000x reference)
//
#include <hip/hip_runtime.h>
#include <math.h>

#define NPTS   65536   // B*P
#define NV     5023
#define LATD   32

// ---------------- Kernel 1: NN search + gshift + feature build ----------------
// grid 256 x 256 threads, 1 thread per point.
__global__ __launch_bounds__(256) void k_nn_feat(
    const float* __restrict__ pts, const float* __restrict__ dm,
    const float* __restrict__ cano, const float* __restrict__ lat,
    float* __restrict__ wsI, float* __restrict__ base3)
{
  __shared__ float4 sV[512];
  const int tid = threadIdx.x;
  const int g   = blockIdx.x * 256 + tid;
  const int b   = g >> 15;                       // P = 32768, uniform per block
  const float* __restrict__ dmb = dm + b * NV * 3;

  const float px = pts[g*3+0], py = pts[g*3+1], pz = pts[g*3+2];
  const float p2 = px*px + py*py + pz*pz;

  float best = 3.4e38f; int bidx = 0;
  for (int v0 = 0; v0 < NV; v0 += 512) {
    __syncthreads();
    for (int i = tid; i < 512; i += 256) {
      const int v = v0 + i;
      float4 t;
      if (v < NV) {
        const float x = dmb[v*3+0], y = dmb[v*3+1], z = dmb[v*3+2];
        t = make_float4(x, y, z, fmaf(x, x, fmaf(y, y, z*z)));
      } else {
        t = make_float4(0.f, 0.f, 0.f, 3.0e38f);   // never wins argmin
      }
      sV[i] = t;
    }
    __syncthreads();
    #pragma unroll 8
    for (int i = 0; i < 512; ++i) {
      const float4 t = sV[i];                      // LDS broadcast (free)
      const float dot = fmaf(px, t.x, fmaf(py, t.y, pz * t.z));
      float d2 = fmaf(-2.f, dot, p2 + t.w);        // p2 + v2 - 2*dot (ref formula)
      d2 = fmaxf(d2, 0.f);
      if (d2 < best) { best = d2; bidx = v0 + i; } // strict < => first-index ties
    }
  }

  const float wgt = expf(-best);
  const float sx = (cano[bidx*3+0] - dmb[bidx*3+0]) * wgt;
  const float sy = (cano[bidx*3+1] - dmb[bidx*3+1]) * wgt;
  const float sz = (cano[bidx*3+2] - dmb[bidx*3+2]) * wgt;

  base3[g*3+0] = px + sx;
  base3[g*3+1] = py + sy;
  base3[g*3+2] = pz + sz;

  // initial features, k-major (column-major) wsI[k][g]; coalesced per-k writes.
  wsI[0*NPTS + g] = px; wsI[1*NPTS + g] = py; wsI[2*NPTS + g] = pz;
  int k = 3;
  #pragma unroll
  for (int f = 0; f < 10; ++f) {
    const float F = (float)(1 << f);
    float s0,c0,s1,c1,s2,c2;
    sincosf(px*F, &s0, &c0); sincosf(py*F, &s1, &c1); sincosf(pz*F, &s2, &c2);
    wsI[(k+0)*NPTS+g]=s0; wsI[(k+1)*NPTS+g]=s1; wsI[(k+2)*NPTS+g]=s2;
    wsI[(k+3)*NPTS+g]=c0; wsI[(k+4)*NPTS+g]=c1; wsI[(k+5)*NPTS+g]=c2;
    k += 6;
  }
  wsI[63*NPTS+g]=sx; wsI[64*NPTS+g]=sy; wsI[65*NPTS+g]=sz;
  k = 66;
  #pragma unroll
  for (int f = 0; f < 2; ++f) {
    const float F = (float)(1 << f);
    float s0,c0,s1,c1,s2,c2;
    sincosf(sx*F,&s0,&c0); sincosf(sy*F,&s1,&c1); sincosf(sz*F,&s2,&c2);
    wsI[(k+0)*NPTS+g]=s0; wsI[(k+1)*NPTS+g]=s1; wsI[(k+2)*NPTS+g]=s2;
    wsI[(k+3)*NPTS+g]=c0; wsI[(k+4)*NPTS+g]=c1; wsI[(k+5)*NPTS+g]=c2;
    k += 6;
  }
  #pragma unroll
  for (int j = 0; j < LATD; ++j) wsI[(78+j)*NPTS + g] = lat[g*LATD + j];
  #pragma unroll
  for (int kk = 110; kk < 128; ++kk) wsI[kk*NPTS + g] = 0.f;  // pad to K=128
}

// ---------------- Kernel 2: fused 8-layer MLP + output head ----------------
// 64 points/block, 512 threads, thread tile = 4 points x 4 neurons.
// LDS: sX 32KB (activations) + sWt 16KB (transposed W k-chunk) + sC 8KB = 56KB.

template<bool FROM_WS>
__device__ __forceinline__ void mlp_pass(
    float (&acc)[4][4],
    const float* __restrict__ Wb, const int rs, const int co, const int validK,
    const float* __restrict__ wsI, const int g0,
    float* __restrict__ sX, float* __restrict__ sWt, float* __restrict__ sC,
    const int tid, const int mg, const int ng)
{
  const float4* __restrict__ sWtv = (const float4*)sWt;
  const float4* __restrict__ sXv  = (const float4*)sX;
  const float4* __restrict__ sCv  = (const float4*)sC;
  for (int kc = 0; kc < 4; ++kc) {
    __syncthreads();
    { // stage W chunk transposed: sWt[k_local][n] = W[n][co + kc*32 + k_local]
      const int n = tid >> 2, k0 = (tid & 3) * 8;
      const float* __restrict__ wrow = Wb + n * rs + co;
      #pragma unroll
      for (int e = 0; e < 8; ++e) {
        const int kg = kc*32 + k0 + e;
        sWt[(k0+e)*128 + n] = (kg < validK) ? wrow[kg] : 0.f;
      }
    }
    if (FROM_WS) { // stage X chunk from k-major workspace: sC[m][k_local]
      const int kk = tid >> 4, m4 = (tid & 15) << 2;
      const float4 v = *(const float4*)(wsI + (kc*32 + kk) * NPTS + g0 + m4);
      sC[(m4+0)*32 + kk] = v.x;
      sC[(m4+1)*32 + kk] = v.y;
      sC[(m4+2)*32 + kk] = v.z;
      sC[(m4+3)*32 + kk] = v.w;
    }
    __syncthreads();
    #pragma unroll
    for (int kb = 0; kb < 8; ++kb) {
      float4 xa[4], wv[4];
      #pragma unroll
      for (int i = 0; i < 4; ++i)
        xa[i] = FROM_WS ? sCv[(mg*4+i)*8 + kb] : sXv[(mg*4+i)*32 + kc*8 + kb];
      #pragma unroll
      for (int e = 0; e < 4; ++e)
        wv[e] = sWtv[(kb*4+e)*32 + ng];
      const float* xs = (const float*)xa;
      const float* wf = (const float*)wv;
      #pragma unroll
      for (int e = 0; e < 4; ++e)
        #pragma unroll
        for (int i = 0; i < 4; ++i)
          #pragma unroll
          for (int j = 0; j < 4; ++j)
            acc[i][j] = fmaf(xs[i*4+e], wf[e*4+j], acc[i][j]);
    }
  }
}

__device__ __forceinline__ void zero_acc(float (&acc)[4][4])
{
  #pragma unroll
  for (int i = 0; i < 4; ++i)
    #pragma unroll
    for (int j = 0; j < 4; ++j)
      acc[i][j] = 0.f;
}

__device__ __forceinline__ void store_layer(
    float (&acc)[4][4], const float* __restrict__ bias,
    float* __restrict__ sX, const int mg, const int ng)
{
  __syncthreads();  // all reads of sX finished before overwrite
  #pragma unroll
  for (int i = 0; i < 4; ++i) {
    const int m = mg*4 + i;
    float4 v;
    v.x = fmaxf(acc[i][0] + bias[ng*4+0], 0.f);
    v.y = fmaxf(acc[i][1] + bias[ng*4+1], 0.f);
    v.z = fmaxf(acc[i][2] + bias[ng*4+2], 0.f);
    v.w = fmaxf(acc[i][3] + bias[ng*4+3], 0.f);
    *(float4*)(sX + m*128 + ng*4) = v;
  }
  // next pass's leading __syncthreads orders these writes before reads
}

__global__ __launch_bounds__(512, 4) void k_mlp(
    const float* __restrict__ wsI, const float* __restrict__ base3,
    const float* __restrict__ w0, const float* __restrict__ b0,
    const float* __restrict__ w1, const float* __restrict__ b1,
    const float* __restrict__ w2, const float* __restrict__ b2,
    const float* __restrict__ w3, const float* __restrict__ b3,
    const float* __restrict__ w4, const float* __restrict__ b4,
    const float* __restrict__ w5, const float* __restrict__ b5,
    const float* __restrict__ w6, const float* __restrict__ b6,
    const float* __restrict__ w7, const float* __restrict__ b7,
    const float* __restrict__ w_out, const float* __restrict__ b_out,
    float* __restrict__ out)
{
  __shared__ float sX[64*128];
  __shared__ float sWt[32*128];
  __shared__ float sC[64*32];

  const int tid = threadIdx.x;
  const int mg = tid >> 5, ng = tid & 31;
  const int g0 = blockIdx.x * 64;

  const float* Ws[8] = {w0,w1,w2,w3,w4,w5,w6,w7};
  const float* Bs[8] = {b0,b1,b2,b3,b4,b5,b6,b7};

  float acc[4][4];

  // layer 0: input = initial (from ws, K padded to 128, W zero-padded past 110)
  zero_acc(acc);
  mlp_pass<true>(acc, w0, 110, 0, 110, wsI, g0, sX, sWt, sC, tid, mg, ng);
  store_layer(acc, b0, sX, mg, ng);

  for (int l = 1; l < 7; ++l) {
    zero_acc(acc);
    if (l == 4) {
      // skip layer: concat(initial[110], x[128]) @ w4[128,238]^T
      mlp_pass<true >(acc, Ws[4], 238,   0, 110, wsI, g0, sX, sWt, sC, tid, mg, ng);
      mlp_pass<false>(acc, Ws[4], 238, 110, 128, wsI, g0, sX, sWt, sC, tid, mg, ng);
    } else {
      mlp_pass<false>(acc, Ws[l], 128, 0, 128, wsI, g0, sX, sWt, sC, tid, mg, ng);
    }
    store_layer(acc, Bs[l], sX, mg, ng);
  }

  // layer 7: pre-activation is last_feat (output 1)
  zero_acc(acc);
  mlp_pass<false>(acc, Ws[7], 128, 0, 128, wsI, g0, sX, sWt, sC, tid, mg, ng);

  __syncthreads();
  float* __restrict__ out1 = out + NPTS*3;
  #pragma unroll
  for (int i = 0; i < 4; ++i) {
    const int m = mg*4 + i, g = g0 + m;
    float4 v;
    v.x = acc[i][0] + b7[ng*4+0];
    v.y = acc[i][1] + b7[ng*4+1];
    v.z = acc[i][2] + b7[ng*4+2];
    v.w = acc[i][3] + b7[ng*4+3];
    *(float4*)(out1 + g*128 + ng*4) = v;                    // last_feat (pre-relu)
    float4 r = make_float4(fmaxf(v.x,0.f), fmaxf(v.y,0.f),
                           fmaxf(v.z,0.f), fmaxf(v.w,0.f));
    *(float4*)(sX + m*128 + ng*4) = r;                      // relu for head
  }
  if (tid < 384) sC[tid] = w_out[tid];
  else if (tid < 387) sC[tid] = b_out[tid - 384];
  __syncthreads();

  if (tid < 64) {   // output head: 3 dots of 128 per point
    const int m = tid, g = g0 + m;
    const float4* __restrict__ xr = (const float4*)(sX + m*128);
    const float4* __restrict__ wr = (const float4*)sC;
    float a0=0.f, a1=0.f, a2=0.f;
    #pragma unroll 8
    for (int kk = 0; kk < 32; ++kk) {
      const int k4 = (kk + m) & 31;          // rotate to spread LDS banks
      const float4 x  = xr[k4];
      const float4 wa = wr[k4], wb = wr[32+k4], wc = wr[64+k4];
      a0 = fmaf(x.x,wa.x, fmaf(x.y,wa.y, fmaf(x.z,wa.z, fmaf(x.w,wa.w, a0))));
      a1 = fmaf(x.x,wb.x, fmaf(x.y,wb.y, fmaf(x.z,wb.z, fmaf(x.w,wb.w, a1))));
      a2 = fmaf(x.x,wc.x, fmaf(x.y,wc.y, fmaf(x.z,wc.z, fmaf(x.w,wc.w, a2))));
    }
    out[g*3+0] = base3[g*3+0] + a0 + sC[384];
    out[g*3+1] = base3[g*3+1] + a1 + sC[385];
    out[g*3+2] = base3[g*3+2] + a2 + sC[386];
  }
}

extern "C" void kernel_launch(void* const* d_in, const int* in_sizes, int n_in,
                              void* d_out, int out_size, void* d_ws, size_t ws_size,
                              hipStream_t stream)
{
  const float* pts  = (const float*)d_in[0];
  const float* dm   = (const float*)d_in[1];
  const float* cano = (const float*)d_in[2];
  const float* lat  = (const float*)d_in[3];
  const float* w[8]; const float* b[8];
  for (int i = 0; i < 8; ++i) {
    w[i] = (const float*)d_in[4 + 2*i];
    b[i] = (const float*)d_in[5 + 2*i];
  }
  const float* w_out = (const float*)d_in[20];
  const float* b_out = (const float*)d_in[21];
  float* out = (float*)d_out;

  float* wsI   = (float*)d_ws;          // [128][NPTS] k-major padded features, 32 MB
  float* base3 = wsI + 128 * NPTS;      // [NPTS][3] pts + gshift, 768 KB

  k_nn_feat<<<NPTS/256, 256, 0, stream>>>(pts, dm, cano, lat, wsI, base3);
  k_mlp<<<NPTS/64, 512, 0, stream>>>(wsI, base3,
      w[0],b[0],w[1],b[1],w[2],b[2],w[3],b[3],
      w[4],b[4],w[5],b[5],w[6],b[6],w[7],b[7],
      w_out, b_out, out);
}

// Round 4
// 315.368 us; speedup vs baseline: 1.7389x; 1.7389x over previous
//
#include <hip/hip_runtime.h>
#include <math.h>

typedef unsigned short ushort_t;
typedef unsigned int   uint_t;
typedef __attribute__((ext_vector_type(8))) short bf16x8;
typedef __attribute__((ext_vector_type(4))) float f32x4;

#define NPTS   65536   // B*P
#define NV     5023
#define LATD   32
#define NNBLK  256     // NN blocks; blocks [NNBLK, NNBLK+8) do weight prep
#define KF     110     // real feature dim (padded to 128 with zeros at stage time)

__device__ __forceinline__ ushort_t f2bf(float f) {
  union { float f; unsigned u; } x; x.f = f;
  unsigned r = x.u + 0x7fffu + ((x.u >> 16) & 1u);   // RNE
  return (ushort_t)(r >> 16);
}
__device__ __forceinline__ float bf2f(ushort_t u) {
  union { unsigned u; float f; } x; x.u = ((unsigned)u) << 16;
  return x.f;
}
// fp32 -> (hi,lo) bf16 pair packed in one uint (hi in low16)
__device__ __forceinline__ uint_t packsplit(float v) {
  const ushort_t h = f2bf(v);
  const ushort_t l = f2bf(v - bf2f(h));
  return (uint_t)h | ((uint_t)l << 16);
}

// Weight panel offsets (ushort units per plane), all K=128 x N=128:
// L0:0 L1:16384 L2:32768 L3:49152 L4a(initial):65536 L4b(x):81920 L5:98304 L6:114688 L7:131072

// ------------- Kernel 1: NN search + packed features (+ weight hi/lo prep) -------------
__global__ __launch_bounds__(256) void k_nn_feat(
    const float* __restrict__ pts, const float* __restrict__ dm,
    const float* __restrict__ cano, const float* __restrict__ lat,
    const float* __restrict__ w0, const float* __restrict__ w1,
    const float* __restrict__ w2, const float* __restrict__ w3,
    const float* __restrict__ w4, const float* __restrict__ w5,
    const float* __restrict__ w6, const float* __restrict__ w7,
    uint_t* __restrict__ wsIp, float* __restrict__ base3,
    ushort_t* __restrict__ wsWh, ushort_t* __restrict__ wsWl)
{
  const int tid = threadIdx.x;

  if (blockIdx.x >= NNBLK) {   // ---- weight prep: fp32 -> bf16 hi/lo, zero-padded ----
    const int l = blockIdx.x - NNBLK;
    const float* Wsrc[8] = {w0,w1,w2,w3,w4,w5,w6,w7};
    const float* __restrict__ src = Wsrc[l];
    const int Kp = (l == 4) ? 256 : 128;
    const int tot = 128 * Kp;
    for (int idx = tid; idx < tot; idx += 256) {
      const int n = idx / Kp, k = idx - n * Kp;
      float v; int dst;
      if (l == 4) {
        if (k < 128) { dst = 65536 + n*128 + k;        v = (k < KF) ? src[n*238 + k] : 0.f; }
        else         { dst = 81920 + n*128 + (k-128);  v = src[n*238 + KF + (k-128)]; }
      } else {
        dst = ((l < 4) ? l*16384 : 98304 + (l-5)*16384) + n*128 + k;
        v = (l == 0) ? ((k < KF) ? src[n*110 + k] : 0.f) : src[n*128 + k];
      }
      const ushort_t h = f2bf(v);
      wsWh[dst] = h;
      wsWl[dst] = f2bf(v - bf2f(h));
    }
    return;
  }

  // ---- NN search: 8 points/thread, 8-way vertex split (verified round 3) ----
  __shared__ float4 sV[512];
  const int s     = tid & 7;
  const int pbase = blockIdx.x * 256 + (tid >> 3) * 8;
  const int b     = blockIdx.x >> 7;               // 128 blocks per batch
  const float* __restrict__ dmb = dm + b * NV * 3;

  float px[8], py[8], pz[8], p2[8], best[8]; int bidx[8];
  #pragma unroll
  for (int j = 0; j < 8; ++j) {
    px[j] = pts[(pbase+j)*3+0]; py[j] = pts[(pbase+j)*3+1]; pz[j] = pts[(pbase+j)*3+2];
    p2[j] = fmaf(px[j],px[j], fmaf(py[j],py[j], pz[j]*pz[j]));
    best[j] = 3.4e38f; bidx[j] = 0;
  }

  for (int v0 = 0; v0 < NV; v0 += 512) {
    __syncthreads();
    for (int i = tid; i < 512; i += 256) {
      const int v = v0 + i;
      float4 t;
      if (v < NV) {
        const float x = dmb[v*3+0], y = dmb[v*3+1], z = dmb[v*3+2];
        t = make_float4(x, y, z, fmaf(x,x, fmaf(y,y, z*z)));
      } else {
        t = make_float4(0.f, 0.f, 0.f, 3.0e38f);
      }
      sV[i] = t;
    }
    __syncthreads();
    #pragma unroll 4
    for (int k = 0; k < 64; ++k) {
      const float4 t = sV[k*8 + s];
      const int vi = v0 + k*8 + s;
      #pragma unroll
      for (int j = 0; j < 8; ++j) {
        const float dot = fmaf(px[j], t.x, fmaf(py[j], t.y, pz[j]*t.z));
        float d2 = fmaf(-2.f, dot, p2[j] + t.w);
        d2 = fmaxf(d2, 0.f);
        if (d2 < best[j]) { best[j] = d2; bidx[j] = vi; }
      }
    }
  }

  #pragma unroll
  for (int off = 1; off <= 4; off <<= 1) {
    #pragma unroll
    for (int j = 0; j < 8; ++j) {
      const float ob = __shfl_xor(best[j], off, 64);
      const int   oi = __shfl_xor(bidx[j], off, 64);
      const bool take = (ob < best[j]) || ((ob == best[j]) && (oi < bidx[j]));
      if (take) { best[j] = ob; bidx[j] = oi; }
    }
  }

  float bb = best[0]; int bi = bidx[0];
  #pragma unroll
  for (int j = 1; j < 8; ++j) if (s == j) { bb = best[j]; bi = bidx[j]; }

  const int g = blockIdx.x * 256 + tid;
  const float qx = pts[g*3+0], qy = pts[g*3+1], qz = pts[g*3+2];

  const float wgt = expf(-bb);
  const float sx = (cano[bi*3+0] - dmb[bi*3+0]) * wgt;
  const float sy = (cano[bi*3+1] - dmb[bi*3+1]) * wgt;
  const float sz = (cano[bi*3+2] - dmb[bi*3+2]) * wgt;

  base3[g*3+0] = qx + sx;
  base3[g*3+1] = qy + sy;
  base3[g*3+2] = qz + sz;

  // packed (hi|lo) features, k-major wsIp[k][g], only k < 110
  wsIp[0*(size_t)NPTS+g] = packsplit(qx);
  wsIp[1*(size_t)NPTS+g] = packsplit(qy);
  wsIp[2*(size_t)NPTS+g] = packsplit(qz);
  int k = 3;
  #pragma unroll
  for (int f = 0; f < 10; ++f) {
    const float F = (float)(1 << f);
    float s0,c0,s1,c1,s2,c2;
    sincosf(qx*F,&s0,&c0); sincosf(qy*F,&s1,&c1); sincosf(qz*F,&s2,&c2);
    wsIp[(size_t)(k+0)*NPTS+g]=packsplit(s0); wsIp[(size_t)(k+1)*NPTS+g]=packsplit(s1);
    wsIp[(size_t)(k+2)*NPTS+g]=packsplit(s2); wsIp[(size_t)(k+3)*NPTS+g]=packsplit(c0);
    wsIp[(size_t)(k+4)*NPTS+g]=packsplit(c1); wsIp[(size_t)(k+5)*NPTS+g]=packsplit(c2);
    k += 6;
  }
  wsIp[63*(size_t)NPTS+g]=packsplit(sx); wsIp[64*(size_t)NPTS+g]=packsplit(sy);
  wsIp[65*(size_t)NPTS+g]=packsplit(sz);
  k = 66;
  #pragma unroll
  for (int f = 0; f < 2; ++f) {
    const float F = (float)(1 << f);
    float s0,c0,s1,c1,s2,c2;
    sincosf(sx*F,&s0,&c0); sincosf(sy*F,&s1,&c1); sincosf(sz*F,&s2,&c2);
    wsIp[(size_t)(k+0)*NPTS+g]=packsplit(s0); wsIp[(size_t)(k+1)*NPTS+g]=packsplit(s1);
    wsIp[(size_t)(k+2)*NPTS+g]=packsplit(s2); wsIp[(size_t)(k+3)*NPTS+g]=packsplit(c0);
    wsIp[(size_t)(k+4)*NPTS+g]=packsplit(c1); wsIp[(size_t)(k+5)*NPTS+g]=packsplit(c2);
    k += 6;
  }
  #pragma unroll
  for (int j = 0; j < LATD; ++j) wsIp[(size_t)(78+j)*NPTS + g] = packsplit(lat[g*LATD + j]);
}

// ------------- Kernel 2: fused MLP, bf16 hi/lo 3-term MFMA -------------
// M=128 pts/block, 512 threads = 8 waves in 2(row) x 4(col) grid; wave tile 64x32.

__device__ __forceinline__ void stage_W(ushort_t* __restrict__ sWh, ushort_t* __restrict__ sWl,
    const ushort_t* __restrict__ gh0, const ushort_t* __restrict__ gl0, int tid)
{
  const uint4* __restrict__ gh = (const uint4*)gh0;   // [128][128] bf16 = 2048 x 16B
  const uint4* __restrict__ gl = (const uint4*)gl0;
  #pragma unroll
  for (int it = 0; it < 4; ++it) {
    const int c = it*512 + tid;
    const int n = c >> 4, kb = c & 15;
    *(uint4*)(sWh + n*136 + kb*8) = gh[c];
    *(uint4*)(sWl + n*136 + kb*8) = gl[c];
  }
}

__device__ __forceinline__ void stage_X(ushort_t* __restrict__ sXh, ushort_t* __restrict__ sXl,
    const uint_t* __restrict__ wsIp, int g0, int tid)
{
  #pragma unroll
  for (int it = 0; it < 32; ++it) {
    const int idx = it*512 + tid;          // 0..16383
    const int k = idx >> 7, m = idx & 127;
    uint_t u = 0;
    if (k < KF) u = wsIp[(size_t)k*NPTS + g0 + m];
    sXh[m*136 + k] = (ushort_t)(u & 0xffffu);
    sXl[m*136 + k] = (ushort_t)(u >> 16);
  }
}

__device__ __forceinline__ void zero_acc(f32x4 (&acc)[4][2]) {
  #pragma unroll
  for (int i = 0; i < 4; ++i)
    #pragma unroll
    for (int j = 0; j < 2; ++j)
      acc[i][j] = (f32x4){0.f,0.f,0.f,0.f};
}

__device__ __forceinline__ void mfma_panel(f32x4 (&acc)[4][2],
    const ushort_t* __restrict__ sXh, const ushort_t* __restrict__ sXl,
    const ushort_t* __restrict__ sWh, const ushort_t* __restrict__ sWl,
    int mq, int nq, int l15, int kq)
{
  #pragma unroll
  for (int ks = 0; ks < 4; ++ks) {
    const int ko = ks*32 + kq;
    bf16x8 bh[2], bl[2], ah[4], al[4];
    #pragma unroll
    for (int nt = 0; nt < 2; ++nt) {
      const int n = nq*32 + nt*16 + l15;
      bh[nt] = *(const bf16x8*)(sWh + n*136 + ko);
      bl[nt] = *(const bf16x8*)(sWl + n*136 + ko);
    }
    #pragma unroll
    for (int mt = 0; mt < 4; ++mt) {
      const int m = mq*64 + mt*16 + l15;
      ah[mt] = *(const bf16x8*)(sXh + m*136 + ko);
      al[mt] = *(const bf16x8*)(sXl + m*136 + ko);
    }
    #pragma unroll
    for (int mt = 0; mt < 4; ++mt)
      #pragma unroll
      for (int nt = 0; nt < 2; ++nt) {
        acc[mt][nt] = __builtin_amdgcn_mfma_f32_16x16x32_bf16(ah[mt], bh[nt], acc[mt][nt], 0,0,0);
        acc[mt][nt] = __builtin_amdgcn_mfma_f32_16x16x32_bf16(al[mt], bh[nt], acc[mt][nt], 0,0,0);
        acc[mt][nt] = __builtin_amdgcn_mfma_f32_16x16x32_bf16(ah[mt], bl[nt], acc[mt][nt], 0,0,0);
      }
  }
}

__device__ __forceinline__ void epi_relu_split(f32x4 (&acc)[4][2],
    ushort_t* __restrict__ sXh, ushort_t* __restrict__ sXl,
    const float* __restrict__ bias, int mq, int nq, int quad, int l15)
{
  #pragma unroll
  for (int mt = 0; mt < 4; ++mt)
    #pragma unroll
    for (int nt = 0; nt < 2; ++nt) {
      const int n = nq*32 + nt*16 + l15;
      const float bv = bias[n];
      #pragma unroll
      for (int r = 0; r < 4; ++r) {
        const int m = mq*64 + mt*16 + quad*4 + r;
        const float v = fmaxf(acc[mt][nt][r] + bv, 0.f);
        const ushort_t h = f2bf(v);
        sXh[m*136 + n] = h;
        sXl[m*136 + n] = f2bf(v - bf2f(h));
      }
    }
}

__global__ __launch_bounds__(512) void k_mlp(
    const uint_t* __restrict__ wsIp, const float* __restrict__ base3,
    const ushort_t* __restrict__ wsWh, const ushort_t* __restrict__ wsWl,
    const float* __restrict__ b0, const float* __restrict__ b1,
    const float* __restrict__ b2, const float* __restrict__ b3,
    const float* __restrict__ b4, const float* __restrict__ b5,
    const float* __restrict__ b6, const float* __restrict__ b7,
    const float* __restrict__ w_out, const float* __restrict__ b_out,
    float* __restrict__ out)
{
  __shared__ __align__(16) ushort_t sXh[128*136];     // 34.8 KB
  __shared__ __align__(16) ushort_t sXl[128*136];     // 34.8 KB
  __shared__ __align__(16) ushort_t sW2[2*128*136];   // 69.6 KB (hi plane, lo plane)
  __shared__ float sB[8*128 + 384 + 4];               // biases + w_out + b_out

  ushort_t* sWh = sW2;
  ushort_t* sWl = sW2 + 128*136;

  const int tid  = threadIdx.x;
  const int lane = tid & 63, wid = tid >> 6;
  const int quad = lane >> 4, l15 = lane & 15, kq = quad*8;
  const int mq = wid & 1, nq = wid >> 1;      // 2 x 4 wave grid
  const int g0 = blockIdx.x * 128;

  f32x4 acc[4][2];

  // ---- P0: layer 0 (initial) ----
  stage_W(sWh, sWl, wsWh + 0, wsWl + 0, tid);
  stage_X(sXh, sXl, wsIp, g0, tid);
  {
    const float* bs[8] = {b0,b1,b2,b3,b4,b5,b6,b7};
    if (tid < 128) {
      #pragma unroll
      for (int l = 0; l < 8; ++l) sB[l*128 + tid] = bs[l][tid];
    } else {
      sB[1024 + (tid - 128)] = w_out[tid - 128];   // 384 values
    }
    if (tid < 3) sB[1408 + tid] = b_out[tid];
  }
  __syncthreads();
  zero_acc(acc);
  mfma_panel(acc, sXh, sXl, sWh, sWl, mq, nq, l15, kq);
  __syncthreads();
  epi_relu_split(acc, sXh, sXl, sB + 0, mq, nq, quad, l15);

  // ---- P1..P3: layers 1..3 ----
  for (int l = 1; l <= 3; ++l) {
    __syncthreads();
    stage_W(sWh, sWl, wsWh + l*16384, wsWl + l*16384, tid);
    __syncthreads();
    zero_acc(acc);
    mfma_panel(acc, sXh, sXl, sWh, sWl, mq, nq, l15, kq);
    __syncthreads();
    epi_relu_split(acc, sXh, sXl, sB + l*128, mq, nq, quad, l15);
  }

  // ---- P4b: layer 4, x part (no epilogue, keep acc) ----
  __syncthreads();
  stage_W(sWh, sWl, wsWh + 81920, wsWl + 81920, tid);
  __syncthreads();
  zero_acc(acc);
  mfma_panel(acc, sXh, sXl, sWh, sWl, mq, nq, l15, kq);

  // ---- P4a: layer 4, initial part (reload initial over sX), accumulate ----
  __syncthreads();
  stage_W(sWh, sWl, wsWh + 65536, wsWl + 65536, tid);
  stage_X(sXh, sXl, wsIp, g0, tid);
  __syncthreads();
  mfma_panel(acc, sXh, sXl, sWh, sWl, mq, nq, l15, kq);
  __syncthreads();
  epi_relu_split(acc, sXh, sXl, sB + 4*128, mq, nq, quad, l15);

  // ---- P5,P6: layers 5..6 ----
  for (int l = 5; l <= 6; ++l) {
    __syncthreads();
    stage_W(sWh, sWl, wsWh + 98304 + (l-5)*16384, wsWl + 98304 + (l-5)*16384, tid);
    __syncthreads();
    zero_acc(acc);
    mfma_panel(acc, sXh, sXl, sWh, sWl, mq, nq, l15, kq);
    __syncthreads();
    epi_relu_split(acc, sXh, sXl, sB + l*128, mq, nq, quad, l15);
  }

  // ---- P8: layer 7 (pre-activation = last_feat) ----
  __syncthreads();
  stage_W(sWh, sWl, wsWh + 131072, wsWl + 131072, tid);
  __syncthreads();
  zero_acc(acc);
  mfma_panel(acc, sXh, sXl, sWh, sWl, mq, nq, l15, kq);

  // last_feat out (fp32), relu kept in acc
  float* __restrict__ out1 = out + (size_t)NPTS*3;
  #pragma unroll
  for (int mt = 0; mt < 4; ++mt)
    #pragma unroll
    for (int nt = 0; nt < 2; ++nt) {
      const int n = nq*32 + nt*16 + l15;
      const float bv = sB[7*128 + n];
      #pragma unroll
      for (int r = 0; r < 4; ++r) {
        const int m = mq*64 + mt*16 + quad*4 + r;
        const float v = acc[mt][nt][r] + bv;
        out1[(size_t)(g0 + m)*128 + n] = v;
        acc[mt][nt][r] = fmaxf(v, 0.f);
      }
    }

  __syncthreads();                      // all sW reads done -> safe to overlay
  float* __restrict__ sF = (float*)sW2; // [128][132] fp32 relu activations
  #pragma unroll
  for (int mt = 0; mt < 4; ++mt)
    #pragma unroll
    for (int nt = 0; nt < 2; ++nt) {
      const int n = nq*32 + nt*16 + l15;
      #pragma unroll
      for (int r = 0; r < 4; ++r) {
        const int m = mq*64 + mt*16 + quad*4 + r;
        sF[m*132 + n] = acc[mt][nt][r];
      }
    }
  __syncthreads();

  if (tid < 384) {                      // head: (point m, component c) per thread
    const int m = tid / 3, c = tid - m*3;
    const float* __restrict__ xr = sF + m*132;
    const float* __restrict__ wc = sB + 1024 + c*128;
    float a = 0.f;
    #pragma unroll 8
    for (int k = 0; k < 128; ++k) a = fmaf(xr[k], wc[k], a);
    const int g = g0 + m;
    out[g*3 + c] = base3[g*3 + c] + a + sB[1408 + c];
  }
}

extern "C" void kernel_launch(void* const* d_in, const int* in_sizes, int n_in,
                              void* d_out, int out_size, void* d_ws, size_t ws_size,
                              hipStream_t stream)
{
  const float* pts  = (const float*)d_in[0];
  const float* dm   = (const float*)d_in[1];
  const float* cano = (const float*)d_in[2];
  const float* lat  = (const float*)d_in[3];
  const float* w[8]; const float* b[8];
  for (int i = 0; i < 8; ++i) {
    w[i] = (const float*)d_in[4 + 2*i];
    b[i] = (const float*)d_in[5 + 2*i];
  }
  const float* w_out = (const float*)d_in[20];
  const float* b_out = (const float*)d_in[21];
  float* out = (float*)d_out;

  // ws layout: wsIp [110][NPTS] uint (28.84 MB) | base3 (786 KB) | wsWh (288 KB) | wsWl (288 KB)
  uint_t*   wsIp  = (uint_t*)d_ws;
  float*    base3 = (float*)((char*)d_ws + (size_t)KF*NPTS*4);
  ushort_t* wsWh  = (ushort_t*)((char*)base3 + (size_t)NPTS*3*4);
  ushort_t* wsWl  = wsWh + 147456;

  k_nn_feat<<<NNBLK + 8, 256, 0, stream>>>(pts, dm, cano, lat,
      w[0],w[1],w[2],w[3],w[4],w[5],w[6],w[7], wsIp, base3, wsWh, wsWl);
  k_mlp<<<NPTS/128, 512, 0, stream>>>(wsIp, base3, wsWh, wsWl,
      b[0],b[1],b[2],b[3],b[4],b[5],b[6],b[7], w_out, b_out, out);
}